// Round 7
// baseline (247.803 us; speedup 1.0000x reference)
//
#include <hip/hip_runtime.h>
#include <math.h>

// Math reduction (EPS=1e-12 negligible for x ~ N(0,1)):
//   gain_j = logit x_j exactly; base = sum_j softplus(x_j);
//   pos = sum_{m=1, x>0} x ; best = max_{m=1} x
//   per_sample = base - (pos>0 ? pos : best);  answer = mean over rows.
//
// Round-7: nt loads (round-6's win: broke the 2.65 TB/s L1-allocation wall)
// + one WAVE per row. Each wave issues 8 nt dwordx4 loads back-to-back
// (~62 cache lines in flight vs 16 in round 6), no LDS, no __syncthreads,
// lane-0 writes partial[row]. 8192 blocks x 4 waves = 32768 rows exactly.

constexpr int B = 32768;
constexpr int C = 1000;
constexpr int THREADS = 256;
constexpr int TAIL = 250 - 192;   // 58 lanes have a 4th float4 chunk

typedef float f32x4 __attribute__((ext_vector_type(4)));

__device__ __forceinline__ void elem_update(float x, float m,
                                            float& base, float& pos, float& best) {
    // softplus(x) = max(x,0) + log(1 + exp(-|x|)); x=-1e30 contributes 0
    float e  = __expf(-fabsf(x));
    float xp = fmaxf(x, 0.0f);
    base += xp + __logf(1.0f + e);
    pos  += m * xp;                       // m in {0,1}
    if (m != 0.0f) best = fmaxf(best, x);
}

__device__ __forceinline__ void vec_update(const f32x4& x, const f32x4& m,
                                           float& base, float& pos, float& best) {
    elem_update(x.x, m.x, base, pos, best);
    elem_update(x.y, m.y, base, pos, best);
    elem_update(x.z, m.z, base, pos, best);
    elem_update(x.w, m.w, base, pos, best);
}

__global__ __launch_bounds__(THREADS)
void row_loss_kernel(const float* __restrict__ X,
                     const float* __restrict__ M,
                     float* __restrict__ partial) {
    const int t    = threadIdx.x;
    const int w    = t >> 6;
    const int lane = t & 63;
    const int row  = blockIdx.x * 4 + w;          // < B by construction

    const f32x4* x4 = reinterpret_cast<const f32x4*>(X + (size_t)row * C);
    const f32x4* m4 = reinterpret_cast<const f32x4*>(M + (size_t)row * C);

    // 8 nt loads in flight per lane (6 unconditional + 2 tail-masked)
    f32x4 x0 = __builtin_nontemporal_load(x4 + lane);
    f32x4 x1 = __builtin_nontemporal_load(x4 + lane + 64);
    f32x4 x2 = __builtin_nontemporal_load(x4 + lane + 128);
    f32x4 m0 = __builtin_nontemporal_load(m4 + lane);
    f32x4 m1 = __builtin_nontemporal_load(m4 + lane + 64);
    f32x4 m2 = __builtin_nontemporal_load(m4 + lane + 128);
    f32x4 x3 = {-1e30f, -1e30f, -1e30f, -1e30f};  // softplus -> 0
    f32x4 m3 = {0.f, 0.f, 0.f, 0.f};
    if (lane < TAIL) {
        x3 = __builtin_nontemporal_load(x4 + lane + 192);
        m3 = __builtin_nontemporal_load(m4 + lane + 192);
    }

    // independent accumulator sets for ILP
    float b0 = 0.f, b1 = 0.f, b2 = 0.f, b3 = 0.f;
    float p0 = 0.f, p1 = 0.f, p2 = 0.f, p3 = 0.f;
    float s0 = -INFINITY, s1 = -INFINITY, s2 = -INFINITY, s3 = -INFINITY;

    vec_update(x0, m0, b0, p0, s0);
    vec_update(x1, m1, b1, p1, s1);
    vec_update(x2, m2, b2, p2, s2);
    vec_update(x3, m3, b3, p3, s3);

    float base = (b0 + b1) + (b2 + b3);
    float pos  = (p0 + p1) + (p2 + p3);
    float best = fmaxf(fmaxf(s0, s1), fmaxf(s2, s3));

    #pragma unroll
    for (int off = 32; off > 0; off >>= 1) {
        base += __shfl_down(base, off, 64);
        pos  += __shfl_down(pos,  off, 64);
        best  = fmaxf(best, __shfl_down(best, off, 64));
    }

    if (lane == 0)
        partial[row] = base - ((pos > 0.f) ? pos : best);
}

// Stage 1: 64 blocks x 256 threads; block b reduces partial[512b .. 512b+511]
__global__ __launch_bounds__(256)
void finalize1_kernel(const float* __restrict__ partial, float* __restrict__ mid) {
    const int b = blockIdx.x;
    const int t = threadIdx.x;
    float v = partial[b * 512 + t] + partial[b * 512 + t + 256];

    #pragma unroll
    for (int off = 32; off > 0; off >>= 1)
        v += __shfl_down(v, off, 64);

    __shared__ float s[4];
    const int w    = t >> 6;
    const int lane = t & 63;
    if (lane == 0) s[w] = v;
    __syncthreads();
    if (t == 0) mid[b] = (s[0] + s[1]) + (s[2] + s[3]);
}

// Stage 2: 1 block x 64 threads; double-precision sum, mean.
__global__ __launch_bounds__(64)
void finalize2_kernel(const float* __restrict__ mid, float* __restrict__ out) {
    double v = (double)mid[threadIdx.x];
    #pragma unroll
    for (int off = 32; off > 0; off >>= 1)
        v += __shfl_down(v, off, 64);
    if (threadIdx.x == 0) out[0] = (float)(v / (double)B);
}

extern "C" void kernel_launch(void* const* d_in, const int* in_sizes, int n_in,
                              void* d_out, int out_size, void* d_ws, size_t ws_size,
                              hipStream_t stream) {
    const float* X  = (const float*)d_in[0];
    const float* M  = (const float*)d_in[1];
    float* out      = (float*)d_out;
    float* partial  = (float*)d_ws;          // 32768 floats
    float* mid      = partial + B;           // 64 floats

    row_loss_kernel<<<B / 4, THREADS, 0, stream>>>(X, M, partial);
    finalize1_kernel<<<64, 256, 0, stream>>>(partial, mid);
    finalize2_kernel<<<1, 64, 0, stream>>>(mid, out);
}